// Round 3
// baseline (374.359 us; speedup 1.0000x reference)
//
#include <hip/hip_runtime.h>
#include <hip/hip_bf16.h>

// Problem constants (B=4, V=4096, D=256, H=4, Dh=64, KNN=10, TOPK=4, HID=64)
#define VV 4096
#define DDIM 256
#define KNN_K 10
#define TK 4

// fp32 helpers forbidding contraction (bit-faithful np mimicry — DO NOT CHANGE)
__device__ __forceinline__ float f_sq3(float x, float y, float z) {
    return __fadd_rn(__fadd_rn(__fmul_rn(x, x), __fmul_rn(y, y)), __fmul_rn(z, z));
}
__device__ __forceinline__ float f_dot3(float ax, float ay, float az,
                                        float bx, float by, float bz) {
    float d = __fmul_rn(ax, bx);
    d = __fmaf_rn(ay, by, d);
    d = __fmaf_rn(az, bz, d);
    return d;
}

// Monotone float->uint flip: u64 key (flip(d2)<<32)|idx gives EXACT lexicographic
// (d2 float-<, then lowest idx) ordering. d2 is never -0.0 (RN subtract), NaN-free.
__device__ __forceinline__ unsigned long long mkkey(float d2, int j) {
    unsigned u = __float_as_uint(d2);
    u ^= (unsigned)((int)u >> 31) | 0x80000000u;
    return ((unsigned long long)u << 32) | (unsigned)j;
}

// ===========================================================================
// K0: AN = tok @ W1[0:512] (no bias)  +  cxyzs[m] = (x,y,z,|c|^2) float4 pack.
// AN[v][0:64] anchor chain (bit-identical sequential fmaf k=0..255 from 0),
// AN[v][64:128] neighbor chain (seed 0; seed-add in K1). grid(256,2) blk 256.
// ===========================================================================
__global__ void __launch_bounds__(256) an_gemm_kernel(
    const float* __restrict__ tok,
    const float* __restrict__ W1,
    const float* __restrict__ coords,
    float* __restrict__ AN,
    float4* __restrict__ cxyzs)
{
    __shared__ float As[16][68];   // [k][m]
    __shared__ float Bs[16][68];   // [k][n]

    const int mBlock = blockIdx.x * 64;
    const int grp    = blockIdx.y;              // 0 = anchor cols, 1 = neighbor cols
    const float* W   = W1 + (size_t)grp * 256 * 64;

    const int tid = threadIdx.x;

    // side job: packed coords + squared norm (bit-identical f_sq3), 16384 total
    if (grp == 0 && tid < 64) {
        int m = mBlock + tid;
        float x = coords[m * 3 + 0], y = coords[m * 3 + 1], z = coords[m * 3 + 2];
        cxyzs[m] = make_float4(x, y, z, f_sq3(x, y, z));
    }

    const int tx = tid & 15;     // n-dir
    const int ty = tid >> 4;     // m-dir

    const int ar  = tid >> 2;          // 0..63 (m row)
    const int ac4 = tid & 3;           // 0..3  (k float4)
    const int br  = tid >> 4;          // 0..15 (k row)
    const int bc4 = tid & 15;          // 0..15 (n float4)

    float acc[4][4] = {};

    for (int k0 = 0; k0 < 256; k0 += 16) {
        float4 a4 = *(const float4*)&tok[(size_t)(mBlock + ar) * 256 + k0 + ac4 * 4];
        As[ac4 * 4 + 0][ar] = a4.x;
        As[ac4 * 4 + 1][ar] = a4.y;
        As[ac4 * 4 + 2][ar] = a4.z;
        As[ac4 * 4 + 3][ar] = a4.w;
        float4 b4 = *(const float4*)&W[(size_t)(k0 + br) * 64 + bc4 * 4];
        *(float4*)&Bs[br][bc4 * 4] = b4;
        __syncthreads();
        #pragma unroll
        for (int kk = 0; kk < 16; kk++) {
            float4 av = *(const float4*)&As[kk][ty * 4];
            float4 bv4 = *(const float4*)&Bs[kk][tx * 4];
            acc[0][0] = fmaf(av.x, bv4.x, acc[0][0]); acc[0][1] = fmaf(av.x, bv4.y, acc[0][1]);
            acc[0][2] = fmaf(av.x, bv4.z, acc[0][2]); acc[0][3] = fmaf(av.x, bv4.w, acc[0][3]);
            acc[1][0] = fmaf(av.y, bv4.x, acc[1][0]); acc[1][1] = fmaf(av.y, bv4.y, acc[1][1]);
            acc[1][2] = fmaf(av.y, bv4.z, acc[1][2]); acc[1][3] = fmaf(av.y, bv4.w, acc[1][3]);
            acc[2][0] = fmaf(av.z, bv4.x, acc[2][0]); acc[2][1] = fmaf(av.z, bv4.y, acc[2][1]);
            acc[2][2] = fmaf(av.z, bv4.z, acc[2][2]); acc[2][3] = fmaf(av.z, bv4.w, acc[2][3]);
            acc[3][0] = fmaf(av.w, bv4.x, acc[3][0]); acc[3][1] = fmaf(av.w, bv4.y, acc[3][1]);
            acc[3][2] = fmaf(av.w, bv4.z, acc[3][2]); acc[3][3] = fmaf(av.w, bv4.w, acc[3][3]);
        }
        __syncthreads();
    }

    #pragma unroll
    for (int i = 0; i < 4; i++) {
        int m = mBlock + ty * 4 + i;
        float4 o;
        o.x = acc[i][0]; o.y = acc[i][1]; o.z = acc[i][2]; o.w = acc[i][3];
        *(float4*)&AN[(size_t)m * 128 + grp * 64 + tx * 4] = o;
    }
}

// ===========================================================================
// K1 (r15): heterogeneous knn + qkv in ONE launch, grid 4864.
// Per 19-block group: 16 knn blocks (4 wave-queries each) + 3 qkv blocks
// (128x128 tile, 8x8/thread). Independent work co-scheduled so qkv's dense
// FMA waves fill knn's latency bubbles. Block-uniform branch; LDS union.
// knn selection arithmetic identical to r14 (cxyzs values copied verbatim,
// same d2/key/extraction sequence).
// ===========================================================================
__global__ void __launch_bounds__(256) knn_qkv_kernel(
    const float* __restrict__ AN,
    const float4* __restrict__ cxyzs,
    const float* __restrict__ W1,
    const float* __restrict__ b1,
    const float* __restrict__ W2,
    int* __restrict__ sel,
    const float* __restrict__ tok,
    const float* __restrict__ Wq, const float* __restrict__ bq,
    const float* __restrict__ Wk, const float* __restrict__ bk,
    const float* __restrict__ Wv, const float* __restrict__ bv,
    float* __restrict__ qkv)
{
    __shared__ __align__(16) char smem[16896];   // max(knn 10720, qkv 16896)
    const int tid   = threadIdx.x;
    const int g     = blockIdx.x;
    const int group = g / 19;
    const int rem   = g - group * 19;

    if (rem < 16) {
        // ---------------- KNN + score path (one wave per query) ----------------
        const int kb   = group * 16 + rem;        // 0..4095
        const int lane = tid & 63;
        const int wave = tid >> 6;
        const int q    = kb * 4 + wave;           // 0..16383
        const int base = q & ~4095;
        const int v    = q & 4095;
        const float4* cx = cxyzs + base;

        int*   sKnn = (int*)smem;                 // [4][10]
        float* sSc  = (float*)(smem + 160);       // [4][10]
        float* sHid = (float*)(smem + 320);       // [4][10][65]

        float4 cq = cx[v];
        const float qx = cq.x, qy = cq.y, qz = cq.z, sqq = cq.w;

        unsigned long long best   = ~0ull;
        unsigned long long second = ~0ull;
        unsigned long long used   = 0ull;

        #pragma unroll 4
        for (int i = 0; i < 64; i++) {
            int j = i * 64 + lane;
            float4 c = cx[j];
            float dt  = f_dot3(qx, qy, qz, c.x, c.y, c.z);
            float d2v = __fsub_rn(__fadd_rn(sqq, c.w), __fmul_rn(2.0f, dt));
            unsigned long long k = mkkey(d2v, j);
            if (k < best) { second = best; best = k; }
            else if (k < second) { second = k; }
        }

        #pragma unroll 1
        for (int it = 0; it < 11; it++) {
            unsigned long long rb = best;
            #pragma unroll
            for (int off = 1; off < 64; off <<= 1) {   // wave butterfly min
                unsigned olo = __shfl_xor((unsigned)rb, off);
                unsigned ohi = __shfl_xor((unsigned)(rb >> 32), off);
                unsigned long long o = ((unsigned long long)ohi << 32) | olo;
                if (o < rb) rb = o;
            }
            int wj = (int)((unsigned)rb & 4095u);
            if (it >= 1 && lane == 0) sKnn[wave * KNN_K + it - 1] = wj;

            if ((unsigned)best == (unsigned)rb) {      // this lane owned the winner
                used |= 1ull << (wj >> 6);
                best = second;
                second = ~0ull;
                if (best == ~0ull) {                   // rare: rescan unconsumed
                    #pragma unroll 1
                    for (int i = 0; i < 64; i++) {
                        if ((used >> i) & 1ull) continue;
                        int j = i * 64 + lane;
                        float4 c = cx[j];
                        float dt  = f_dot3(qx, qy, qz, c.x, c.y, c.z);
                        float d2v = __fsub_rn(__fadd_rn(sqq, c.w), __fmul_rn(2.0f, dt));
                        unsigned long long k = mkkey(d2v, j);
                        if (k < best) { second = best; best = k; }
                        else if (k < second) { second = k; }
                    }
                }
            }
        }

        // ---------------- Phase B: gather-based score MLP (lane == h) ----------
        const float sAl = AN[(size_t)q * 128 + lane];
        const float b1l = b1[lane];
        const float wr0 = W1[(512 + 0) * 64 + lane];
        const float wr1 = W1[(512 + 1) * 64 + lane];
        const float wr2 = W1[(512 + 2) * 64 + lane];

        #pragma unroll 1
        for (int nb = 0; nb < KNN_K; nb++) {
            int kn = sKnn[wave * KNN_K + nb];
            float4 cn = cx[kn];
            float acc = __fadd_rn(sAl, AN[(size_t)(base + kn) * 128 + 64 + lane]);
            float rel0 = __fsub_rn(cn.x, qx);
            acc = __fmaf_rn(rel0, wr0, acc);
            float rel1 = __fsub_rn(cn.y, qy);
            acc = __fmaf_rn(rel1, wr1, acc);
            float rel2 = __fsub_rn(cn.z, qz);
            acc = __fmaf_rn(rel2, wr2, acc);
            float hid = __fadd_rn(acc, b1l);
            sHid[(wave * KNN_K + nb) * 65 + lane] = hid > 0.0f ? hid : 0.0f;
        }

        // sequential-chain scorer, EXACT r13 rounding (lanes 0..9, wave-sync)
        if (lane < KNN_K) {
            float s = 0.0f;
            #pragma unroll 8
            for (int h = 0; h < 64; h++)
                s = __fmaf_rn(sHid[(wave * KNN_K + lane) * 65 + h], W2[h], s);
            sSc[wave * KNN_K + lane] = s;
        }

        if (lane == 0) {          // stable top-4 -> global rows
            unsigned um = 0;
            #pragma unroll
            for (int s = 0; s < TK; s++) {
                float bests = -3.4e38f; int bj = 0;
                for (int jj = 0; jj < KNN_K; jj++) {
                    if (um & (1u << jj)) continue;
                    float sc = sSc[wave * KNN_K + jj];
                    if (sc > bests) { bests = sc; bj = jj; }
                }
                um |= 1u << bj;
                sel[(size_t)q * TK + s] = base + sKnn[wave * KNN_K + bj];
            }
        }
    } else {
        // ---------------- QKV GEMM path: 128x128 tile, 8x8/thread -------------
        float* As = (float*)smem;                 // [16][132]
        float* Bs = (float*)smem + 16 * 132;      // [16][132]

        const int id     = group * 3 + (rem - 16);   // 0..767
        const int mBlock = (id & 127) * 128;
        const int nb     = id >> 7;                  // 0..5
        const int grp    = nb >> 1;                  // 0=Q,1=K,2=V
        const int nIn    = (nb & 1) * 128;           // 0 or 128
        const float* W    = (grp == 0) ? Wq : (grp == 1) ? Wk : Wv;
        const float* bias = (grp == 0) ? bq : (grp == 1) ? bk : bv;

        const int tx = tid & 15;     // n-dir
        const int ty = tid >> 4;     // m-dir
        const int ar  = tid >> 2;    // 0..63 (m row, +64 second)
        const int ac4 = tid & 3;     // 0..3  (k float4)
        const int br  = tid >> 4;    // 0..15 (k row)
        const int bc4 = tid & 15;    // 0..15 (n float4, +64 second)

        float acc[2][2][4][4] = {};  // [mi][ni][i][j]

        for (int k0 = 0; k0 < 256; k0 += 16) {
            float4 a0 = *(const float4*)&tok[(size_t)(mBlock + ar) * 256 + k0 + ac4 * 4];
            float4 a1 = *(const float4*)&tok[(size_t)(mBlock + 64 + ar) * 256 + k0 + ac4 * 4];
            As[(ac4 * 4 + 0) * 132 + ar] = a0.x;      As[(ac4 * 4 + 0) * 132 + 64 + ar] = a1.x;
            As[(ac4 * 4 + 1) * 132 + ar] = a0.y;      As[(ac4 * 4 + 1) * 132 + 64 + ar] = a1.y;
            As[(ac4 * 4 + 2) * 132 + ar] = a0.z;      As[(ac4 * 4 + 2) * 132 + 64 + ar] = a1.z;
            As[(ac4 * 4 + 3) * 132 + ar] = a0.w;      As[(ac4 * 4 + 3) * 132 + 64 + ar] = a1.w;
            float4 b0 = *(const float4*)&W[(size_t)(k0 + br) * 256 + nIn + bc4 * 4];
            float4 b1v = *(const float4*)&W[(size_t)(k0 + br) * 256 + nIn + 64 + bc4 * 4];
            *(float4*)&Bs[br * 132 + bc4 * 4] = b0;
            *(float4*)&Bs[br * 132 + 64 + bc4 * 4] = b1v;
            __syncthreads();
            #pragma unroll
            for (int kk = 0; kk < 16; kk++) {
                float4 av0 = *(const float4*)&As[kk * 132 + ty * 4];
                float4 av1 = *(const float4*)&As[kk * 132 + 64 + ty * 4];
                float4 bv0 = *(const float4*)&Bs[kk * 132 + tx * 4];
                float4 bv1 = *(const float4*)&Bs[kk * 132 + 64 + tx * 4];
                const float am[2][4] = {{av0.x, av0.y, av0.z, av0.w},
                                        {av1.x, av1.y, av1.z, av1.w}};
                const float bn[2][4] = {{bv0.x, bv0.y, bv0.z, bv0.w},
                                        {bv1.x, bv1.y, bv1.z, bv1.w}};
                #pragma unroll
                for (int mi = 0; mi < 2; mi++)
                #pragma unroll
                for (int i = 0; i < 4; i++)
                #pragma unroll
                for (int ni = 0; ni < 2; ni++)
                #pragma unroll
                for (int j = 0; j < 4; j++)
                    acc[mi][ni][i][j] = fmaf(am[mi][i], bn[ni][j], acc[mi][ni][i][j]);
            }
            __syncthreads();
        }

        #pragma unroll
        for (int mi = 0; mi < 2; mi++)
        #pragma unroll
        for (int i = 0; i < 4; i++) {
            int m = mBlock + mi * 64 + ty * 4 + i;
            #pragma unroll
            for (int ni = 0; ni < 2; ni++) {
                int col = nIn + ni * 64 + tx * 4;
                float4 o;
                o.x = acc[mi][ni][i][0] + bias[col + 0];
                o.y = acc[mi][ni][i][1] + bias[col + 1];
                o.z = acc[mi][ni][i][2] + bias[col + 2];
                o.w = acc[mi][ni][i][3] + bias[col + 3];
                *(float4*)&qkv[(size_t)m * 768 + grp * 256 + col] = o;
            }
        }
    }
}

// ===========================================================================
// K3: gather 4 selected K/V rows, 4-head attention -> attnout[q][256].
// ===========================================================================
__global__ void __launch_bounds__(256) attn_gather_kernel(
    const float* __restrict__ qkv, const int* __restrict__ sel,
    float* __restrict__ attnout)
{
    const int q = blockIdx.x;
    const int tid = threadIdx.x;  // = h*64 + dh

    const float qv = qkv[(size_t)q * 768 + tid];

    int rows[TK];
    #pragma unroll
    for (int s = 0; s < TK; s++) rows[s] = sel[(size_t)q * TK + s];

    float att[TK];
    #pragma unroll
    for (int s = 0; s < TK; s++) {
        float p = qv * qkv[(size_t)rows[s] * 768 + 256 + tid];
        #pragma unroll
        for (int m = 1; m < 64; m <<= 1) p += __shfl_xor(p, m);
        att[s] = p * 0.125f;   // 1/sqrt(64)
    }

    float mx  = fmaxf(fmaxf(att[0], att[1]), fmaxf(att[2], att[3]));
    float e0 = expf(att[0] - mx), e1 = expf(att[1] - mx),
          e2 = expf(att[2] - mx), e3 = expf(att[3] - mx);
    float inv = 1.0f / (e0 + e1 + e2 + e3);

    float o = (e0 * qkv[(size_t)rows[0] * 768 + 512 + tid] +
               e1 * qkv[(size_t)rows[1] * 768 + 512 + tid] +
               e2 * qkv[(size_t)rows[2] * 768 + 512 + tid] +
               e3 * qkv[(size_t)rows[3] * 768 + 512 + tid]) * inv;

    attnout[(size_t)q * 256 + tid] = o;
}

// ===========================================================================
// K4: output projection GEMM, 128x128 tile / 8x8 per thread.
// out = attnout @ Wo + bo. M=16384, N=256, K=256. grid(128,2).
// ===========================================================================
__global__ void __launch_bounds__(256) wo_gemm_kernel(
    const float* __restrict__ A,
    const float* __restrict__ Wo, const float* __restrict__ bo,
    float* __restrict__ out)
{
    __shared__ float As[16][132];
    __shared__ float Bs[16][132];

    const int mBlock = blockIdx.x * 128;
    const int nBlock = blockIdx.y * 128;     // 0 or 128

    const int tid = threadIdx.x;
    const int tx = tid & 15;
    const int ty = tid >> 4;
    const int ar  = tid >> 2;
    const int ac4 = tid & 3;
    const int br  = tid >> 4;
    const int bc4 = tid & 15;

    float acc[2][2][4][4] = {};

    for (int k0 = 0; k0 < 256; k0 += 16) {
        float4 a0 = *(const float4*)&A[(size_t)(mBlock + ar) * 256 + k0 + ac4 * 4];
        float4 a1 = *(const float4*)&A[(size_t)(mBlock + 64 + ar) * 256 + k0 + ac4 * 4];
        As[ac4 * 4 + 0][ar] = a0.x;      As[ac4 * 4 + 0][64 + ar] = a1.x;
        As[ac4 * 4 + 1][ar] = a0.y;      As[ac4 * 4 + 1][64 + ar] = a1.y;
        As[ac4 * 4 + 2][ar] = a0.z;      As[ac4 * 4 + 2][64 + ar] = a1.z;
        As[ac4 * 4 + 3][ar] = a0.w;      As[ac4 * 4 + 3][64 + ar] = a1.w;
        float4 b0 = *(const float4*)&Wo[(size_t)(k0 + br) * 256 + nBlock + bc4 * 4];
        float4 b1v = *(const float4*)&Wo[(size_t)(k0 + br) * 256 + nBlock + 64 + bc4 * 4];
        *(float4*)&Bs[br][bc4 * 4] = b0;
        *(float4*)&Bs[br][64 + bc4 * 4] = b1v;
        __syncthreads();
        #pragma unroll
        for (int kk = 0; kk < 16; kk++) {
            float4 av0 = *(const float4*)&As[kk][ty * 4];
            float4 av1 = *(const float4*)&As[kk][64 + ty * 4];
            float4 bv0 = *(const float4*)&Bs[kk][tx * 4];
            float4 bv1 = *(const float4*)&Bs[kk][64 + tx * 4];
            const float am[2][4] = {{av0.x, av0.y, av0.z, av0.w},
                                    {av1.x, av1.y, av1.z, av1.w}};
            const float bn[2][4] = {{bv0.x, bv0.y, bv0.z, bv0.w},
                                    {bv1.x, bv1.y, bv1.z, bv1.w}};
            #pragma unroll
            for (int mi = 0; mi < 2; mi++)
            #pragma unroll
            for (int i = 0; i < 4; i++)
            #pragma unroll
            for (int ni = 0; ni < 2; ni++)
            #pragma unroll
            for (int j = 0; j < 4; j++)
                acc[mi][ni][i][j] = fmaf(am[mi][i], bn[ni][j], acc[mi][ni][i][j]);
        }
        __syncthreads();
    }

    #pragma unroll
    for (int mi = 0; mi < 2; mi++)
    #pragma unroll
    for (int i = 0; i < 4; i++) {
        int m = mBlock + mi * 64 + ty * 4 + i;
        #pragma unroll
        for (int ni = 0; ni < 2; ni++) {
            int col = nBlock + ni * 64 + tx * 4;
            float4 o;
            o.x = acc[mi][ni][i][0] + bo[col + 0];
            o.y = acc[mi][ni][i][1] + bo[col + 1];
            o.z = acc[mi][ni][i][2] + bo[col + 2];
            o.w = acc[mi][ni][i][3] + bo[col + 3];
            *(float4*)&out[(size_t)m * 256 + col] = o;
        }
    }
}

// ===========================================================================
// Fallback: round-9 fully fused kernel (PASSED @1050us), used if ws too small.
// ===========================================================================
__global__ void __launch_bounds__(256) fused_voxel_attn(
    const float* __restrict__ tok,
    const float* __restrict__ coords,
    const float* __restrict__ W1,
    const float* __restrict__ b1,
    const float* __restrict__ W2,
    const float* __restrict__ Wq, const float* __restrict__ bq,
    const float* __restrict__ Wk, const float* __restrict__ bk,
    const float* __restrict__ Wv, const float* __restrict__ bv,
    const float* __restrict__ Wo, const float* __restrict__ bo,
    float* __restrict__ out, int out_size)
{
    const int q    = blockIdx.x;
    const int b    = q >> 12;
    const int v    = q & 4095;
    const int base = q & ~4095;
    const int tid  = threadIdx.x;
    const float* cb = coords + (size_t)b * VV * 3;

    __shared__ float  sval[256];
    __shared__ int    sidx[256];
    __shared__ int    sKnn[KNN_K];
    __shared__ int    sSel[TK];
    __shared__ float  sTokA[DDIM];
    __shared__ float  sTokN[KNN_K][DDIM];
    __shared__ float  sAH[64];
    __shared__ float  sHid[KNN_K][64];
    __shared__ float  sSc[KNN_K];
    __shared__ float  sP[TK][256];
    __shared__ float  sAtt[4][TK];
    __shared__ float  sO[DDIM];

    const float qx = cb[v * 3 + 0];
    const float qy = cb[v * 3 + 1];
    const float qz = cb[v * 3 + 2];
    const float sqq = f_sq3(qx, qy, qz);

    float d2[16];
    #pragma unroll
    for (int i = 0; i < 16; i++) {
        int j = tid + i * 256;
        float xj = cb[j * 3 + 0], yj = cb[j * 3 + 1], zj = cb[j * 3 + 2];
        float sqj = f_sq3(xj, yj, zj);
        float dt  = f_dot3(qx, qy, qz, xj, yj, zj);
        d2[i] = __fsub_rn(__fadd_rn(sqq, sqj), __fmul_rn(2.0f, dt));
    }

    unsigned used = 0;
    for (int it = 0; it < 11; it++) {
        float best = 3.4e38f;
        int bi = 0x7fffffff;
        #pragma unroll
        for (int i = 0; i < 16; i++) {
            if (used & (1u << i)) continue;
            if (d2[i] < best) { best = d2[i]; bi = tid + i * 256; }
        }
        sval[tid] = best;
        sidx[tid] = bi;
        __syncthreads();
        for (int s = 128; s > 0; s >>= 1) {
            if (tid < s) {
                float v2 = sval[tid + s];
                int   i2 = sidx[tid + s];
                if (v2 < sval[tid] || (v2 == sval[tid] && i2 < sidx[tid])) {
                    sval[tid] = v2; sidx[tid] = i2;
                }
            }
            __syncthreads();
        }
        int w = sidx[0] & 4095;
        __syncthreads();
        if (it >= 1 && tid == 0) sKnn[it - 1] = w;
        if ((w & 255) == tid) used |= 1u << (w >> 8);
    }
    __syncthreads();

    sTokA[tid] = tok[(size_t)q * DDIM + tid];
    for (int nb = 0; nb < KNN_K; nb++)
        sTokN[nb][tid] = tok[(size_t)(base + sKnn[nb]) * DDIM + tid];
    __syncthreads();

    if (tid < 64) {
        float a = 0.0f;
        for (int k = 0; k < 256; k++)
            a = __fmaf_rn(sTokA[k], W1[k * 64 + tid], a);
        sAH[tid] = a;
    }
    __syncthreads();

    for (int idx = tid; idx < KNN_K * 64; idx += 256) {
        int nb = idx >> 6;
        int h  = idx & 63;
        float acc = sAH[h];
        const float* tn = sTokN[nb];
        for (int k = 0; k < 256; k++)
            acc = __fmaf_rn(tn[k], W1[(256 + k) * 64 + h], acc);
        #pragma unroll
        for (int c = 0; c < 3; c++) {
            float rel = __fsub_rn(cb[sKnn[nb] * 3 + c], cb[v * 3 + c]);
            acc = __fmaf_rn(rel, W1[(512 + c) * 64 + h], acc);
        }
        float hid = __fadd_rn(acc, b1[h]);
        sHid[nb][h] = hid > 0.0f ? hid : 0.0f;
    }
    __syncthreads();

    if (tid < KNN_K) {
        float s = 0.0f;
        for (int h = 0; h < 64; h++)
            s = __fmaf_rn(sHid[tid][h], W2[h], s);
        sSc[tid] = s;
    }
    __syncthreads();

    if (tid == 0) {
        unsigned um = 0;
        #pragma unroll
        for (int s = 0; s < TK; s++) {
            float best = -3.4e38f; int bj = 0;
            for (int jj = 0; jj < KNN_K; jj++) {
                if (um & (1u << jj)) continue;
                if (sSc[jj] > best) { best = sSc[jj]; bj = jj; }
            }
            um |= 1u << bj;
            sSel[s] = bj;
        }
    }
    __syncthreads();

    int ss[TK];
    float k_acc[TK], v_acc[TK];
    #pragma unroll
    for (int s = 0; s < TK; s++) {
        ss[s] = sSel[s];
        k_acc[s] = bk[tid];
        v_acc[s] = bv[tid];
    }
    float q_acc = bq[tid];

    for (int k = 0; k < 256; k++) {
        float wq = Wq[k * 256 + tid];
        float wk = Wk[k * 256 + tid];
        float wv = Wv[k * 256 + tid];
        q_acc += sTokA[k] * wq;
        #pragma unroll
        for (int s = 0; s < TK; s++) {
            float x = sTokN[ss[s]][k];
            k_acc[s] += x * wk;
            v_acc[s] += x * wv;
        }
    }

    #pragma unroll
    for (int s = 0; s < TK; s++) sP[s][tid] = q_acc * k_acc[s];
    __syncthreads();

    if (tid < 16) {
        int h = tid >> 2, s = tid & 3;
        float p = 0.0f;
        for (int d = 0; d < 64; d++) p += sP[s][h * 64 + d];
        sAtt[h][s] = p * 0.125f;
    }
    __syncthreads();

    const int hh = tid >> 6;
    float a0 = sAtt[hh][0], a1 = sAtt[hh][1], a2 = sAtt[hh][2], a3 = sAtt[hh][3];
    float mx  = fmaxf(fmaxf(a0, a1), fmaxf(a2, a3));
    float e0 = expf(a0 - mx), e1 = expf(a1 - mx), e2 = expf(a2 - mx), e3 = expf(a3 - mx);
    float inv = 1.0f / (e0 + e1 + e2 + e3);
    float o = (e0 * v_acc[0] + e1 * v_acc[1] + e2 * v_acc[2] + e3 * v_acc[3]) * inv;

    sO[tid] = o;
    __syncthreads();

    float a = bo[tid];
    for (int e = 0; e < 256; e++) a += sO[e] * Wo[e * 256 + tid];
    int oidx = q * DDIM + tid;
    if (oidx < out_size)
        out[oidx] = a;
}

// ---------------------------------------------------------------------------
// Launcher. ABI-bilingual size-walk (validated r8-r11). r15 ws layout:
//   sel     @ 0          : 16384*4*4   =    262,144
//   AN      @ 262,144    : 16384*128*4 =  8,388,608  (ends  8,650,752)
//   attnout @ 262,144    : 16384*256*4 = 16,777,216  (ends 17,039,360) ALIAS of AN
//   qkv     @ 17,039,360 : 16384*768*4 = 50,331,648  (ends 67,371,008)
//   cxyzs   @ 67,371,008 : 16384*16    =    262,144  (ends 67,633,152)
// NEED = 67,633,152 < 75,497,472 (r11-confirmed available).
// Hazards: AN,cxyzs written(K0) -> read(K1); attnout written(K3) after AN
// dead; wo(K4) reads attnout. Same-stream order guarantees safety.
// ---------------------------------------------------------------------------
extern "C" void kernel_launch(void* const* d_in, const int* in_sizes, int n_in,
                              void* d_out, int out_size, void* d_ws, size_t ws_size,
                              hipStream_t stream)
{
    const long long want[13] = {4194304LL, 49152LL, 32960LL, 64LL, 64LL,
                                65536LL, 256LL, 65536LL, 256LL,
                                65536LL, 256LL, 65536LL, 256LL};
    int idx[13];
    const int n = n_in;

    const long long* s64 = (const long long*)(const void*)in_sizes;
    const int*       s32 = in_sizes;

    bool ok = false;

    if (n >= 13 && s64[0] == want[0]) {   // int64 interpretation (gated)
        ok = true;
        int walk = 0;
        for (int t = 0; t < 13; t++) {
            int f = -1;
            for (int i = walk; i < n; i++) {
                if (s64[i] == want[t]) { f = i; break; }
            }
            if (f < 0) { ok = false; break; }
            idx[t] = f; walk = f + 1;
        }
    }

    if (!ok) {                            // int32 interpretation
        ok = true;
        int walk = 0;
        for (int t = 0; t < 13; t++) {
            int f = -1;
            for (int i = walk; i < n; i++) {
                if ((long long)s32[i] == want[t]) { f = i; break; }
            }
            if (f < 0) { ok = false; break; }
            idx[t] = f; walk = f + 1;
        }
    }

    if (!ok) return;   // unexpected layout: clean failure, no crash

    const float* tok    = (const float*)d_in[idx[0]];
    const float* coords = (const float*)d_in[idx[1]];
    const float* W1     = (const float*)d_in[idx[2]];
    const float* b1     = (const float*)d_in[idx[3]];
    const float* W2     = (const float*)d_in[idx[4]];
    const float* Wq     = (const float*)d_in[idx[5]];
    const float* bq     = (const float*)d_in[idx[6]];
    const float* Wk     = (const float*)d_in[idx[7]];
    const float* bk     = (const float*)d_in[idx[8]];
    const float* Wv     = (const float*)d_in[idx[9]];
    const float* bv     = (const float*)d_in[idx[10]];
    const float* Wo     = (const float*)d_in[idx[11]];
    const float* bo     = (const float*)d_in[idx[12]];
    float* out = (float*)d_out;

    const size_t NEED = 67633152;
    if (ws_size >= NEED) {
        char* ws = (char*)d_ws;
        int*    sel     = (int*)   (ws + 0);
        float*  AN      = (float*) (ws + 262144);
        float*  attnout = (float*) (ws + 262144);    // aliases AN (dead after K1)
        float*  qkv     = (float*) (ws + 17039360);
        float4* cxyzs   = (float4*)(ws + 67371008);

        an_gemm_kernel<<<dim3(256, 2), dim3(256), 0, stream>>>(tok, W1, coords, AN, cxyzs);
        knn_qkv_kernel<<<dim3(4864), dim3(256), 0, stream>>>(
            AN, cxyzs, W1, b1, W2, sel, tok, Wq, bq, Wk, bk, Wv, bv, qkv);
        attn_gather_kernel<<<dim3(16384), dim3(256), 0, stream>>>(qkv, sel, attnout);
        wo_gemm_kernel<<<dim3(128, 2), dim3(256), 0, stream>>>(attnout, Wo, bo, out);
    } else {
        fused_voxel_attn<<<dim3(16384), dim3(256), 0, stream>>>(
            tok, coords, W1, b1, W2, Wq, bq, Wk, bk, Wv, bv, Wo, bo, out, out_size);
    }
}

// Round 4
// 367.171 us; speedup vs baseline: 1.0196x; 1.0196x over previous
//
#include <hip/hip_runtime.h>
#include <hip/hip_bf16.h>

// Problem constants (B=4, V=4096, D=256, H=4, Dh=64, KNN=10, TOPK=4, HID=64)
#define VV 4096
#define DDIM 256
#define KNN_K 10
#define TK 4

// fp32 helpers forbidding contraction (bit-faithful np mimicry — DO NOT CHANGE)
__device__ __forceinline__ float f_sq3(float x, float y, float z) {
    return __fadd_rn(__fadd_rn(__fmul_rn(x, x), __fmul_rn(y, y)), __fmul_rn(z, z));
}
__device__ __forceinline__ float f_dot3(float ax, float ay, float az,
                                        float bx, float by, float bz) {
    float d = __fmul_rn(ax, bx);
    d = __fmaf_rn(ay, by, d);
    d = __fmaf_rn(az, bz, d);
    return d;
}

// Monotone float->uint flip: u64 key (flip(d2)<<32)|idx gives EXACT lexicographic
// (d2 float-<, then lowest idx) ordering. d2 is never -0.0 (RN subtract), NaN-free.
__device__ __forceinline__ unsigned long long mkkey(float d2, int j) {
    unsigned u = __float_as_uint(d2);
    u ^= (unsigned)((int)u >> 31) | 0x80000000u;
    return ((unsigned long long)u << 32) | (unsigned)j;
}

// 4x4 fp32 outer-product accumulate, statically indexed (registers guaranteed)
__device__ __forceinline__ void fma44(const float4 a, const float4 b, float (&c)[4][4]) {
    c[0][0] = fmaf(a.x, b.x, c[0][0]); c[0][1] = fmaf(a.x, b.y, c[0][1]);
    c[0][2] = fmaf(a.x, b.z, c[0][2]); c[0][3] = fmaf(a.x, b.w, c[0][3]);
    c[1][0] = fmaf(a.y, b.x, c[1][0]); c[1][1] = fmaf(a.y, b.y, c[1][1]);
    c[1][2] = fmaf(a.y, b.z, c[1][2]); c[1][3] = fmaf(a.y, b.w, c[1][3]);
    c[2][0] = fmaf(a.z, b.x, c[2][0]); c[2][1] = fmaf(a.z, b.y, c[2][1]);
    c[2][2] = fmaf(a.z, b.z, c[2][2]); c[2][3] = fmaf(a.z, b.w, c[2][3]);
    c[3][0] = fmaf(a.w, b.x, c[3][0]); c[3][1] = fmaf(a.w, b.y, c[3][1]);
    c[3][2] = fmaf(a.w, b.z, c[3][2]); c[3][3] = fmaf(a.w, b.w, c[3][3]);
}

// ===========================================================================
// K0: AN = tok @ W1[0:512] (no bias)  +  cxyzs[m] = (x,y,z,|c|^2) float4 pack.
// AN[v][0:64] anchor chain (bit-identical sequential fmaf k=0..255 from 0),
// AN[v][64:128] neighbor chain (seed 0; seed-add in K1). grid(256,2) blk 256.
// ===========================================================================
__global__ void __launch_bounds__(256) an_gemm_kernel(
    const float* __restrict__ tok,
    const float* __restrict__ W1,
    const float* __restrict__ coords,
    float* __restrict__ AN,
    float4* __restrict__ cxyzs)
{
    __shared__ float As[16][68];   // [k][m]
    __shared__ float Bs[16][68];   // [k][n]

    const int mBlock = blockIdx.x * 64;
    const int grp    = blockIdx.y;              // 0 = anchor cols, 1 = neighbor cols
    const float* W   = W1 + (size_t)grp * 256 * 64;

    const int tid = threadIdx.x;

    // side job: packed coords + squared norm (bit-identical f_sq3), 16384 total
    if (grp == 0 && tid < 64) {
        int m = mBlock + tid;
        float x = coords[m * 3 + 0], y = coords[m * 3 + 1], z = coords[m * 3 + 2];
        cxyzs[m] = make_float4(x, y, z, f_sq3(x, y, z));
    }

    const int tx = tid & 15;     // n-dir
    const int ty = tid >> 4;     // m-dir

    const int ar  = tid >> 2;          // 0..63 (m row)
    const int ac4 = tid & 3;           // 0..3  (k float4)
    const int br  = tid >> 4;          // 0..15 (k row)
    const int bc4 = tid & 15;          // 0..15 (n float4)

    float acc[4][4] = {};

    for (int k0 = 0; k0 < 256; k0 += 16) {
        float4 a4 = *(const float4*)&tok[(size_t)(mBlock + ar) * 256 + k0 + ac4 * 4];
        As[ac4 * 4 + 0][ar] = a4.x;
        As[ac4 * 4 + 1][ar] = a4.y;
        As[ac4 * 4 + 2][ar] = a4.z;
        As[ac4 * 4 + 3][ar] = a4.w;
        float4 b4 = *(const float4*)&W[(size_t)(k0 + br) * 64 + bc4 * 4];
        *(float4*)&Bs[br][bc4 * 4] = b4;
        __syncthreads();
        #pragma unroll
        for (int kk = 0; kk < 16; kk++) {
            float4 av = *(const float4*)&As[kk][ty * 4];
            float4 bv4 = *(const float4*)&Bs[kk][tx * 4];
            fma44(av, bv4, acc);
        }
        __syncthreads();
    }

    #pragma unroll
    for (int i = 0; i < 4; i++) {
        int m = mBlock + ty * 4 + i;
        float4 o;
        o.x = acc[i][0]; o.y = acc[i][1]; o.z = acc[i][2]; o.w = acc[i][3];
        *(float4*)&AN[(size_t)m * 128 + grp * 64 + tx * 4] = o;
    }
}

// ===========================================================================
// K1 (r16): standalone wave-per-query KNN + score MLP + top-4. grid 4096.
// float4 cxyzs scan (verified bit-identical in r15). Zero __syncthreads.
// ===========================================================================
__global__ void __launch_bounds__(256) knn_score_kernel(
    const float* __restrict__ AN,
    const float4* __restrict__ cxyzs,
    const float* __restrict__ W1,
    const float* __restrict__ b1,
    const float* __restrict__ W2,
    int* __restrict__ sel)
{
    const int tid  = threadIdx.x;
    const int lane = tid & 63;
    const int wave = tid >> 6;
    const int q    = blockIdx.x * 4 + wave;   // 0..16383
    const int base = q & ~4095;
    const int v    = q & 4095;
    const float4* cx = cxyzs + base;

    __shared__ int   sKnn[4][KNN_K];
    __shared__ float sSc[4][KNN_K];
    __shared__ float sHid[4][KNN_K][65];   // pad 65: scorer stride-65 conflict-free

    float4 cq = cx[v];
    const float qx = cq.x, qy = cq.y, qz = cq.z, sqq = cq.w;

    unsigned long long best   = ~0ull;
    unsigned long long second = ~0ull;
    unsigned long long used   = 0ull;

    #pragma unroll 4
    for (int i = 0; i < 64; i++) {
        int j = i * 64 + lane;
        float4 c = cx[j];
        float dt  = f_dot3(qx, qy, qz, c.x, c.y, c.z);
        float d2v = __fsub_rn(__fadd_rn(sqq, c.w), __fmul_rn(2.0f, dt));
        unsigned long long k = mkkey(d2v, j);
        if (k < best) { second = best; best = k; }
        else if (k < second) { second = k; }
    }

    #pragma unroll 1
    for (int it = 0; it < 11; it++) {
        unsigned long long rb = best;
        #pragma unroll
        for (int off = 1; off < 64; off <<= 1) {   // wave butterfly min (order-free)
            unsigned olo = __shfl_xor((unsigned)rb, off);
            unsigned ohi = __shfl_xor((unsigned)(rb >> 32), off);
            unsigned long long o = ((unsigned long long)ohi << 32) | olo;
            if (o < rb) rb = o;
        }
        int wj = (int)((unsigned)rb & 4095u);
        if (it >= 1 && lane == 0) sKnn[wave][it - 1] = wj;

        if ((unsigned)best == (unsigned)rb) {      // this lane owned the winner
            used |= 1ull << (wj >> 6);
            best = second;
            second = ~0ull;
            if (best == ~0ull) {                   // rare: rescan unconsumed
                #pragma unroll 1
                for (int i = 0; i < 64; i++) {
                    if ((used >> i) & 1ull) continue;
                    int j = i * 64 + lane;
                    float4 c = cx[j];
                    float dt  = f_dot3(qx, qy, qz, c.x, c.y, c.z);
                    float d2v = __fsub_rn(__fadd_rn(sqq, c.w), __fmul_rn(2.0f, dt));
                    unsigned long long k = mkkey(d2v, j);
                    if (k < best) { second = best; best = k; }
                    else if (k < second) { second = k; }
                }
            }
        }
    }

    // ---------------- Phase B: gather-based score MLP (lane == h) ----------
    const float sAl = AN[(size_t)q * 128 + lane];
    const float b1l = b1[lane];
    const float wr0 = W1[(512 + 0) * 64 + lane];
    const float wr1 = W1[(512 + 1) * 64 + lane];
    const float wr2 = W1[(512 + 2) * 64 + lane];

    #pragma unroll 1
    for (int nb = 0; nb < KNN_K; nb++) {
        int kn = sKnn[wave][nb];
        float4 cn = cx[kn];
        float acc = __fadd_rn(sAl, AN[(size_t)(base + kn) * 128 + 64 + lane]);
        float rel0 = __fsub_rn(cn.x, qx);
        acc = __fmaf_rn(rel0, wr0, acc);
        float rel1 = __fsub_rn(cn.y, qy);
        acc = __fmaf_rn(rel1, wr1, acc);
        float rel2 = __fsub_rn(cn.z, qz);
        acc = __fmaf_rn(rel2, wr2, acc);
        float hid = __fadd_rn(acc, b1l);
        sHid[wave][nb][lane] = hid > 0.0f ? hid : 0.0f;
    }

    // sequential-chain scorer, EXACT r13 rounding (lanes 0..9, wave-sync)
    if (lane < KNN_K) {
        float s = 0.0f;
        #pragma unroll 8
        for (int h = 0; h < 64; h++)
            s = __fmaf_rn(sHid[wave][lane][h], W2[h], s);
        sSc[wave][lane] = s;
    }

    if (lane == 0) {          // stable top-4 -> global rows
        unsigned um = 0;
        #pragma unroll
        for (int s = 0; s < TK; s++) {
            float bests = -3.4e38f; int bj = 0;
            for (int jj = 0; jj < KNN_K; jj++) {
                if (um & (1u << jj)) continue;
                float sc = sSc[wave][jj];
                if (sc > bests) { bests = sc; bj = jj; }
            }
            um |= 1u << bj;
            sel[(size_t)q * TK + s] = base + sKnn[wave][bj];
        }
    }
}

// ===========================================================================
// K2 (r16): standalone QKV GEMM, 128x128 tile / 8x8 per thread.
// __launch_bounds__(256,1): relax occupancy target so the 64-acc tile stays
// in arch VGPRs (r15's union kernel spilled it to AGPRs at VGPR_Count=56).
// M=16384, N=768, K=256. grid(128,6).
// ===========================================================================
__global__ void __launch_bounds__(256, 1) qkv_gemm_kernel(
    const float* __restrict__ tok,
    const float* __restrict__ Wq, const float* __restrict__ bq,
    const float* __restrict__ Wk, const float* __restrict__ bk,
    const float* __restrict__ Wv, const float* __restrict__ bv,
    float* __restrict__ qkv)
{
    __shared__ float As[16][132];
    __shared__ float Bs[16][132];

    const int mBlock = blockIdx.x * 128;
    const int nb     = blockIdx.y;            // 0..5
    const int grp    = nb >> 1;               // 0=Q,1=K,2=V
    const int nIn    = (nb & 1) * 128;        // 0 or 128
    const float* W    = (grp == 0) ? Wq : (grp == 1) ? Wk : Wv;
    const float* bias = (grp == 0) ? bq : (grp == 1) ? bk : bv;

    const int tid = threadIdx.x;
    const int tx = tid & 15;     // n-dir
    const int ty = tid >> 4;     // m-dir
    const int ar  = tid >> 2;    // 0..63 (m row, +64 second)
    const int ac4 = tid & 3;     // 0..3  (k float4)
    const int br  = tid >> 4;    // 0..15 (k row)
    const int bc4 = tid & 15;    // 0..15 (n float4, +64 second)

    float acc00[4][4] = {}, acc01[4][4] = {}, acc10[4][4] = {}, acc11[4][4] = {};

    for (int k0 = 0; k0 < 256; k0 += 16) {
        float4 a0 = *(const float4*)&tok[(size_t)(mBlock + ar) * 256 + k0 + ac4 * 4];
        float4 a1 = *(const float4*)&tok[(size_t)(mBlock + 64 + ar) * 256 + k0 + ac4 * 4];
        As[ac4 * 4 + 0][ar] = a0.x;      As[ac4 * 4 + 0][64 + ar] = a1.x;
        As[ac4 * 4 + 1][ar] = a0.y;      As[ac4 * 4 + 1][64 + ar] = a1.y;
        As[ac4 * 4 + 2][ar] = a0.z;      As[ac4 * 4 + 2][64 + ar] = a1.z;
        As[ac4 * 4 + 3][ar] = a0.w;      As[ac4 * 4 + 3][64 + ar] = a1.w;
        float4 b0 = *(const float4*)&W[(size_t)(k0 + br) * 256 + nIn + bc4 * 4];
        float4 b1v = *(const float4*)&W[(size_t)(k0 + br) * 256 + nIn + 64 + bc4 * 4];
        *(float4*)&Bs[br][bc4 * 4] = b0;
        *(float4*)&Bs[br][64 + bc4 * 4] = b1v;
        __syncthreads();
        #pragma unroll
        for (int kk = 0; kk < 16; kk++) {
            float4 av0 = *(const float4*)&As[kk][ty * 4];
            float4 av1 = *(const float4*)&As[kk][64 + ty * 4];
            float4 bv0 = *(const float4*)&Bs[kk][tx * 4];
            float4 bv1 = *(const float4*)&Bs[kk][64 + tx * 4];
            fma44(av0, bv0, acc00);
            fma44(av0, bv1, acc01);
            fma44(av1, bv0, acc10);
            fma44(av1, bv1, acc11);
        }
        __syncthreads();
    }

    #pragma unroll
    for (int i = 0; i < 4; i++) {
        int m0 = mBlock + ty * 4 + i;
        int m1 = m0 + 64;
        int c0 = nIn + tx * 4;
        int c1 = c0 + 64;
        float4 o;
        o.x = acc00[i][0] + bias[c0 + 0]; o.y = acc00[i][1] + bias[c0 + 1];
        o.z = acc00[i][2] + bias[c0 + 2]; o.w = acc00[i][3] + bias[c0 + 3];
        *(float4*)&qkv[(size_t)m0 * 768 + grp * 256 + c0] = o;
        o.x = acc01[i][0] + bias[c1 + 0]; o.y = acc01[i][1] + bias[c1 + 1];
        o.z = acc01[i][2] + bias[c1 + 2]; o.w = acc01[i][3] + bias[c1 + 3];
        *(float4*)&qkv[(size_t)m0 * 768 + grp * 256 + c1] = o;
        o.x = acc10[i][0] + bias[c0 + 0]; o.y = acc10[i][1] + bias[c0 + 1];
        o.z = acc10[i][2] + bias[c0 + 2]; o.w = acc10[i][3] + bias[c0 + 3];
        *(float4*)&qkv[(size_t)m1 * 768 + grp * 256 + c0] = o;
        o.x = acc11[i][0] + bias[c1 + 0]; o.y = acc11[i][1] + bias[c1 + 1];
        o.z = acc11[i][2] + bias[c1 + 2]; o.w = acc11[i][3] + bias[c1 + 3];
        *(float4*)&qkv[(size_t)m1 * 768 + grp * 256 + c1] = o;
    }
}

// ===========================================================================
// K3 (r16): wave-per-query attention gather. grid 4096, 4 queries/block.
// Butterfly-sum order identical to r14/r15 (bit-identical per head).
// ===========================================================================
__global__ void __launch_bounds__(256) attn_gather_kernel(
    const float* __restrict__ qkv, const int* __restrict__ sel,
    float* __restrict__ attnout)
{
    const int tid  = threadIdx.x;
    const int lane = tid & 63;
    const int wave = tid >> 6;
    const int q    = blockIdx.x * 4 + wave;

    int rows[TK];
    #pragma unroll
    for (int s = 0; s < TK; s++) rows[s] = sel[(size_t)q * TK + s];

    const float* qrow = qkv + (size_t)q * 768;

    #pragma unroll
    for (int h = 0; h < 4; h++) {
        const int d = h * 64 + lane;
        const float qv = qrow[d];

        float att[TK];
        #pragma unroll
        for (int s = 0; s < TK; s++) {
            float p = qv * qkv[(size_t)rows[s] * 768 + 256 + d];
            #pragma unroll
            for (int m = 1; m < 64; m <<= 1) p += __shfl_xor(p, m);
            att[s] = p * 0.125f;   // 1/sqrt(64)
        }

        float mx  = fmaxf(fmaxf(att[0], att[1]), fmaxf(att[2], att[3]));
        float e0 = expf(att[0] - mx), e1 = expf(att[1] - mx),
              e2 = expf(att[2] - mx), e3 = expf(att[3] - mx);
        float inv = 1.0f / (e0 + e1 + e2 + e3);

        float o = (e0 * qkv[(size_t)rows[0] * 768 + 512 + d] +
                   e1 * qkv[(size_t)rows[1] * 768 + 512 + d] +
                   e2 * qkv[(size_t)rows[2] * 768 + 512 + d] +
                   e3 * qkv[(size_t)rows[3] * 768 + 512 + d]) * inv;

        attnout[(size_t)q * 256 + d] = o;
    }
}

// ===========================================================================
// K4 (r16): output projection GEMM, 128x128 tile / 8x8, launch_bounds(256,1).
// out = attnout @ Wo + bo. M=16384, N=256, K=256. grid(128,2).
// ===========================================================================
__global__ void __launch_bounds__(256, 1) wo_gemm_kernel(
    const float* __restrict__ A,
    const float* __restrict__ Wo, const float* __restrict__ bo,
    float* __restrict__ out)
{
    __shared__ float As[16][132];
    __shared__ float Bs[16][132];

    const int mBlock = blockIdx.x * 128;
    const int nBlock = blockIdx.y * 128;     // 0 or 128

    const int tid = threadIdx.x;
    const int tx = tid & 15;
    const int ty = tid >> 4;
    const int ar  = tid >> 2;
    const int ac4 = tid & 3;
    const int br  = tid >> 4;
    const int bc4 = tid & 15;

    float acc00[4][4] = {}, acc01[4][4] = {}, acc10[4][4] = {}, acc11[4][4] = {};

    for (int k0 = 0; k0 < 256; k0 += 16) {
        float4 a0 = *(const float4*)&A[(size_t)(mBlock + ar) * 256 + k0 + ac4 * 4];
        float4 a1 = *(const float4*)&A[(size_t)(mBlock + 64 + ar) * 256 + k0 + ac4 * 4];
        As[ac4 * 4 + 0][ar] = a0.x;      As[ac4 * 4 + 0][64 + ar] = a1.x;
        As[ac4 * 4 + 1][ar] = a0.y;      As[ac4 * 4 + 1][64 + ar] = a1.y;
        As[ac4 * 4 + 2][ar] = a0.z;      As[ac4 * 4 + 2][64 + ar] = a1.z;
        As[ac4 * 4 + 3][ar] = a0.w;      As[ac4 * 4 + 3][64 + ar] = a1.w;
        float4 b0 = *(const float4*)&Wo[(size_t)(k0 + br) * 256 + nBlock + bc4 * 4];
        float4 b1v = *(const float4*)&Wo[(size_t)(k0 + br) * 256 + nBlock + 64 + bc4 * 4];
        *(float4*)&Bs[br][bc4 * 4] = b0;
        *(float4*)&Bs[br][64 + bc4 * 4] = b1v;
        __syncthreads();
        #pragma unroll
        for (int kk = 0; kk < 16; kk++) {
            float4 av0 = *(const float4*)&As[kk][ty * 4];
            float4 av1 = *(const float4*)&As[kk][64 + ty * 4];
            float4 bv0 = *(const float4*)&Bs[kk][tx * 4];
            float4 bv1 = *(const float4*)&Bs[kk][64 + tx * 4];
            fma44(av0, bv0, acc00);
            fma44(av0, bv1, acc01);
            fma44(av1, bv0, acc10);
            fma44(av1, bv1, acc11);
        }
        __syncthreads();
    }

    #pragma unroll
    for (int i = 0; i < 4; i++) {
        int m0 = mBlock + ty * 4 + i;
        int m1 = m0 + 64;
        int c0 = nBlock + tx * 4;
        int c1 = c0 + 64;
        float4 o;
        o.x = acc00[i][0] + bo[c0 + 0]; o.y = acc00[i][1] + bo[c0 + 1];
        o.z = acc00[i][2] + bo[c0 + 2]; o.w = acc00[i][3] + bo[c0 + 3];
        *(float4*)&out[(size_t)m0 * 256 + c0] = o;
        o.x = acc01[i][0] + bo[c1 + 0]; o.y = acc01[i][1] + bo[c1 + 1];
        o.z = acc01[i][2] + bo[c1 + 2]; o.w = acc01[i][3] + bo[c1 + 3];
        *(float4*)&out[(size_t)m0 * 256 + c1] = o;
        o.x = acc10[i][0] + bo[c0 + 0]; o.y = acc10[i][1] + bo[c0 + 1];
        o.z = acc10[i][2] + bo[c0 + 2]; o.w = acc10[i][3] + bo[c0 + 3];
        *(float4*)&out[(size_t)m1 * 256 + c0] = o;
        o.x = acc11[i][0] + bo[c1 + 0]; o.y = acc11[i][1] + bo[c1 + 1];
        o.z = acc11[i][2] + bo[c1 + 2]; o.w = acc11[i][3] + bo[c1 + 3];
        *(float4*)&out[(size_t)m1 * 256 + c1] = o;
    }
}

// ===========================================================================
// Fallback: round-9 fully fused kernel (PASSED @1050us), used if ws too small.
// ===========================================================================
__global__ void __launch_bounds__(256) fused_voxel_attn(
    const float* __restrict__ tok,
    const float* __restrict__ coords,
    const float* __restrict__ W1,
    const float* __restrict__ b1,
    const float* __restrict__ W2,
    const float* __restrict__ Wq, const float* __restrict__ bq,
    const float* __restrict__ Wk, const float* __restrict__ bk,
    const float* __restrict__ Wv, const float* __restrict__ bv,
    const float* __restrict__ Wo, const float* __restrict__ bo,
    float* __restrict__ out, int out_size)
{
    const int q    = blockIdx.x;
    const int b    = q >> 12;
    const int v    = q & 4095;
    const int base = q & ~4095;
    const int tid  = threadIdx.x;
    const float* cb = coords + (size_t)b * VV * 3;

    __shared__ float  sval[256];
    __shared__ int    sidx[256];
    __shared__ int    sKnn[KNN_K];
    __shared__ int    sSel[TK];
    __shared__ float  sTokA[DDIM];
    __shared__ float  sTokN[KNN_K][DDIM];
    __shared__ float  sAH[64];
    __shared__ float  sHid[KNN_K][64];
    __shared__ float  sSc[KNN_K];
    __shared__ float  sP[TK][256];
    __shared__ float  sAtt[4][TK];
    __shared__ float  sO[DDIM];

    const float qx = cb[v * 3 + 0];
    const float qy = cb[v * 3 + 1];
    const float qz = cb[v * 3 + 2];
    const float sqq = f_sq3(qx, qy, qz);

    float d2[16];
    #pragma unroll
    for (int i = 0; i < 16; i++) {
        int j = tid + i * 256;
        float xj = cb[j * 3 + 0], yj = cb[j * 3 + 1], zj = cb[j * 3 + 2];
        float sqj = f_sq3(xj, yj, zj);
        float dt  = f_dot3(qx, qy, qz, xj, yj, zj);
        d2[i] = __fsub_rn(__fadd_rn(sqq, sqj), __fmul_rn(2.0f, dt));
    }

    unsigned used = 0;
    for (int it = 0; it < 11; it++) {
        float best = 3.4e38f;
        int bi = 0x7fffffff;
        #pragma unroll
        for (int i = 0; i < 16; i++) {
            if (used & (1u << i)) continue;
            if (d2[i] < best) { best = d2[i]; bi = tid + i * 256; }
        }
        sval[tid] = best;
        sidx[tid] = bi;
        __syncthreads();
        for (int s = 128; s > 0; s >>= 1) {
            if (tid < s) {
                float v2 = sval[tid + s];
                int   i2 = sidx[tid + s];
                if (v2 < sval[tid] || (v2 == sval[tid] && i2 < sidx[tid])) {
                    sval[tid] = v2; sidx[tid] = i2;
                }
            }
            __syncthreads();
        }
        int w = sidx[0] & 4095;
        __syncthreads();
        if (it >= 1 && tid == 0) sKnn[it - 1] = w;
        if ((w & 255) == tid) used |= 1u << (w >> 8);
    }
    __syncthreads();

    sTokA[tid] = tok[(size_t)q * DDIM + tid];
    for (int nb = 0; nb < KNN_K; nb++)
        sTokN[nb][tid] = tok[(size_t)(base + sKnn[nb]) * DDIM + tid];
    __syncthreads();

    if (tid < 64) {
        float a = 0.0f;
        for (int k = 0; k < 256; k++)
            a = __fmaf_rn(sTokA[k], W1[k * 64 + tid], a);
        sAH[tid] = a;
    }
    __syncthreads();

    for (int idx = tid; idx < KNN_K * 64; idx += 256) {
        int nb = idx >> 6;
        int h  = idx & 63;
        float acc = sAH[h];
        const float* tn = sTokN[nb];
        for (int k = 0; k < 256; k++)
            acc = __fmaf_rn(tn[k], W1[(256 + k) * 64 + h], acc);
        #pragma unroll
        for (int c = 0; c < 3; c++) {
            float rel = __fsub_rn(cb[sKnn[nb] * 3 + c], cb[v * 3 + c]);
            acc = __fmaf_rn(rel, W1[(512 + c) * 64 + h], acc);
        }
        float hid = __fadd_rn(acc, b1[h]);
        sHid[nb][h] = hid > 0.0f ? hid : 0.0f;
    }
    __syncthreads();

    if (tid < KNN_K) {
        float s = 0.0f;
        for (int h = 0; h < 64; h++)
            s = __fmaf_rn(sHid[tid][h], W2[h], s);
        sSc[tid] = s;
    }
    __syncthreads();

    if (tid == 0) {
        unsigned um = 0;
        #pragma unroll
        for (int s = 0; s < TK; s++) {
            float best = -3.4e38f; int bj = 0;
            for (int jj = 0; jj < KNN_K; jj++) {
                if (um & (1u << jj)) continue;
                if (sSc[jj] > best) { best = sSc[jj]; bj = jj; }
            }
            um |= 1u << bj;
            sSel[s] = bj;
        }
    }
    __syncthreads();

    int ss[TK];
    float k_acc[TK], v_acc[TK];
    #pragma unroll
    for (int s = 0; s < TK; s++) {
        ss[s] = sSel[s];
        k_acc[s] = bk[tid];
        v_acc[s] = bv[tid];
    }
    float q_acc = bq[tid];

    for (int k = 0; k < 256; k++) {
        float wq = Wq[k * 256 + tid];
        float wk = Wk[k * 256 + tid];
        float wv = Wv[k * 256 + tid];
        q_acc += sTokA[k] * wq;
        #pragma unroll
        for (int s = 0; s < TK; s++) {
            float x = sTokN[ss[s]][k];
            k_acc[s] += x * wk;
            v_acc[s] += x * wv;
        }
    }

    #pragma unroll
    for (int s = 0; s < TK; s++) sP[s][tid] = q_acc * k_acc[s];
    __syncthreads();

    if (tid < 16) {
        int h = tid >> 2, s = tid & 3;
        float p = 0.0f;
        for (int d = 0; d < 64; d++) p += sP[s][h * 64 + d];
        sAtt[h][s] = p * 0.125f;
    }
    __syncthreads();

    const int hh = tid >> 6;
    float a0 = sAtt[hh][0], a1 = sAtt[hh][1], a2 = sAtt[hh][2], a3 = sAtt[hh][3];
    float mx  = fmaxf(fmaxf(a0, a1), fmaxf(a2, a3));
    float e0 = expf(a0 - mx), e1 = expf(a1 - mx), e2 = expf(a2 - mx), e3 = expf(a3 - mx);
    float inv = 1.0f / (e0 + e1 + e2 + e3);
    float o = (e0 * v_acc[0] + e1 * v_acc[1] + e2 * v_acc[2] + e3 * v_acc[3]) * inv;

    sO[tid] = o;
    __syncthreads();

    float a = bo[tid];
    for (int e = 0; e < 256; e++) a += sO[e] * Wo[e * 256 + tid];
    int oidx = q * DDIM + tid;
    if (oidx < out_size)
        out[oidx] = a;
}

// ---------------------------------------------------------------------------
// Launcher. ABI-bilingual size-walk (validated r8-r11). r16 ws layout:
//   sel     @ 0          : 16384*4*4   =    262,144
//   AN      @ 262,144    : 16384*128*4 =  8,388,608  (ends  8,650,752)
//   attnout @ 262,144    : 16384*256*4 = 16,777,216  (ends 17,039,360) ALIAS of AN
//   qkv     @ 17,039,360 : 16384*768*4 = 50,331,648  (ends 67,371,008)
//   cxyzs   @ 67,371,008 : 16384*16    =    262,144  (ends 67,633,152)
// NEED = 67,633,152 < 75,497,472 (r11-confirmed available).
// Hazards: AN,cxyzs written(K0) -> read(K1); attnout written(K3) after AN
// dead; wo(K4) reads attnout. Same-stream order guarantees safety.
// ---------------------------------------------------------------------------
extern "C" void kernel_launch(void* const* d_in, const int* in_sizes, int n_in,
                              void* d_out, int out_size, void* d_ws, size_t ws_size,
                              hipStream_t stream)
{
    const long long want[13] = {4194304LL, 49152LL, 32960LL, 64LL, 64LL,
                                65536LL, 256LL, 65536LL, 256LL,
                                65536LL, 256LL, 65536LL, 256LL};
    int idx[13];
    const int n = n_in;

    const long long* s64 = (const long long*)(const void*)in_sizes;
    const int*       s32 = in_sizes;

    bool ok = false;

    if (n >= 13 && s64[0] == want[0]) {   // int64 interpretation (gated)
        ok = true;
        int walk = 0;
        for (int t = 0; t < 13; t++) {
            int f = -1;
            for (int i = walk; i < n; i++) {
                if (s64[i] == want[t]) { f = i; break; }
            }
            if (f < 0) { ok = false; break; }
            idx[t] = f; walk = f + 1;
        }
    }

    if (!ok) {                            // int32 interpretation
        ok = true;
        int walk = 0;
        for (int t = 0; t < 13; t++) {
            int f = -1;
            for (int i = walk; i < n; i++) {
                if ((long long)s32[i] == want[t]) { f = i; break; }
            }
            if (f < 0) { ok = false; break; }
            idx[t] = f; walk = f + 1;
        }
    }

    if (!ok) return;   // unexpected layout: clean failure, no crash

    const float* tok    = (const float*)d_in[idx[0]];
    const float* coords = (const float*)d_in[idx[1]];
    const float* W1     = (const float*)d_in[idx[2]];
    const float* b1     = (const float*)d_in[idx[3]];
    const float* W2     = (const float*)d_in[idx[4]];
    const float* Wq     = (const float*)d_in[idx[5]];
    const float* bq     = (const float*)d_in[idx[6]];
    const float* Wk     = (const float*)d_in[idx[7]];
    const float* bk     = (const float*)d_in[idx[8]];
    const float* Wv     = (const float*)d_in[idx[9]];
    const float* bv     = (const float*)d_in[idx[10]];
    const float* Wo     = (const float*)d_in[idx[11]];
    const float* bo     = (const float*)d_in[idx[12]];
    float* out = (float*)d_out;

    const size_t NEED = 67633152;
    if (ws_size >= NEED) {
        char* ws = (char*)d_ws;
        int*    sel     = (int*)   (ws + 0);
        float*  AN      = (float*) (ws + 262144);
        float*  attnout = (float*) (ws + 262144);    // aliases AN (dead after K1)
        float*  qkv     = (float*) (ws + 17039360);
        float4* cxyzs   = (float4*)(ws + 67371008);

        an_gemm_kernel<<<dim3(256, 2), dim3(256), 0, stream>>>(tok, W1, coords, AN, cxyzs);
        knn_score_kernel<<<dim3(4096), dim3(256), 0, stream>>>(AN, cxyzs, W1, b1, W2, sel);
        qkv_gemm_kernel<<<dim3(128, 6), dim3(256), 0, stream>>>(tok, Wq, bq, Wk, bk, Wv, bv, qkv);
        attn_gather_kernel<<<dim3(4096), dim3(256), 0, stream>>>(qkv, sel, attnout);
        wo_gemm_kernel<<<dim3(128, 2), dim3(256), 0, stream>>>(attnout, Wo, bo, out);
    } else {
        fused_voxel_attn<<<dim3(16384), dim3(256), 0, stream>>>(
            tok, coords, W1, b1, W2, Wq, bq, Wk, bk, Wv, bv, Wo, bo, out, out_size);
    }
}